// Round 9
// baseline (327.964 us; speedup 1.0000x reference)
//
#include <hip/hip_runtime.h>
#include <hip/hip_bf16.h>
#include <utility>

typedef __bf16        bf16x8 __attribute__((ext_vector_type(8)));
typedef float         f32x16 __attribute__((ext_vector_type(16)));
typedef unsigned int  u32x4  __attribute__((ext_vector_type(4)));
typedef unsigned int   u32;
typedef unsigned short u16;

template<int N> using IC = std::integral_constant<int, N>;

__device__ __forceinline__ u16 f32_to_bf16(float f) {
    u32 u = __builtin_bit_cast(u32, f);
    u = (u + 0x7FFFu + ((u >> 16) & 1u)) >> 16;
    return (u16)u;
}
__device__ __forceinline__ u32 pack2bf(float a, float b) {
    return (u32)f32_to_bf16(a) | ((u32)f32_to_bf16(b) << 16);
}

// ---------------- kernel 1: build conv weights, bf16, layout [tap][oc][ic]
__global__ void build_c(const float* __restrict__ wxx,
                        const float* __restrict__ wid,
                        const float* __restrict__ XX,
                        const float* __restrict__ ident,
                        const int*   __restrict__ indsxx,
                        const int*   __restrict__ indsid,
                        u16*         __restrict__ cb)
{
    int idx = blockIdx.x * 256 + threadIdx.x;          // 25*128*128 = 409600
    if (idx >= 25 * 128 * 128) return;
    int b = idx & 127;            // ic2
    int a = (idx >> 7) & 127;     // oc2
    int t = idx >> 14;            // kh*5+kw
    int w2 = (a >> 1) * 64 + (b >> 1);
    float v = wxx[w2 * 5 + indsxx[t]] * XX[(a * 128 + b) * 25 + t]
            + ident[a * 128 + b]      * wid[w2 * 6 + indsid[t]];
    cb[idx] = f32_to_bf16(v);
}

// ---------------- kernel 1b: transpose+pad x -> bf16 xT[b][s][h' 0..131][w' 0..131][32B]
// (h' = h+2, w' = w+2, zero-padded borders; 32B cell = 16 ic of stage s, two 16B halves)
__global__ void transpose_pad(const float* __restrict__ x, u16* __restrict__ xT)
{
    int idx = blockIdx.x * 256 + threadIdx.x;          // 16*8*132*264 = 4,460,544 chunks
    if (idx >= 16 * 8 * 132 * 264) return;
    int c2 = idx % 264;
    int h1 = (idx / 264) % 132;
    int s  = (idx / (264 * 132)) % 8;
    int b  = idx / (264 * 132 * 8);
    int wp = c2 >> 1, half = c2 & 1;
    int h = h1 - 2, w = wp - 2;
    u32x4 v = {0u, 0u, 0u, 0u};
    if ((unsigned)h < 128u && (unsigned)w < 128u) {
        const float* px = x + (((size_t)(b * 128 + s * 16 + half * 8)) * 128 + h) * 128 + w;
        float f[8];
        #pragma unroll
        for (int i = 0; i < 8; ++i) f[i] = px[(size_t)i * 16384];
        v[0] = pack2bf(f[0], f[1]); v[1] = pack2bf(f[2], f[3]);
        v[2] = pack2bf(f[4], f[5]); v[3] = pack2bf(f[6], f[7]);
    }
    *reinterpret_cast<u32x4*>(xT + (size_t)idx * 8) = v;
}

// ---------------- kernel 2: implicit-GEMM conv, 32x32x16 bf16 MFMA, DMA-staged
// 256 thr = 4 waves (2 oc-halves x 2 w-halves). Block: 128 oc x 4 rows x 64 w.
// 8 stages of 16 ic; x staged via global_load_lds from pre-transposed xT (zero VALU).
// LDS buffer: [8 rows][68 w'][32B] = 17408 B, double-buffered. Reads bank-minimal.
// A double-buffered in regs (80 VGPR); stencil B-reuse: 8 ds_read -> 40 MFMA/cluster.
constexpr int ROWB = 68 * 32;          // 2176 B LDS row
constexpr int BUFB = 8 * ROWB;         // 17408 B per buffer
constexpr int GROW = 132 * 32;         // 4224 B global row
constexpr int GSPL = 132 * GROW;       // 557568 B per (b,s) plane
constexpr int GB   = 8 * GSPL;         // per-b stride

__global__ void __launch_bounds__(256, 2)
conv_mfma(const u16* __restrict__ xT,
          const u16* __restrict__ cb,
          float*     __restrict__ out)
{
    __shared__ unsigned char lds[2 * BUFB];

    const int tid    = threadIdx.x;
    const int lane   = tid & 63;
    const int wv     = tid >> 6;
    const int wave_m = wv & 1;                           // oc half of 128
    const int wave_q = wv >> 1;                          // w half of 64
    const int l31    = lane & 31;
    const int h2     = lane >> 5;                        // k-half within K=16

    // bijective XCD swizzle: 1024 blocks, 128 consecutive tiles per XCD
    const int bid  = blockIdx.x;
    const int sbid = (bid & 7) * 128 + (bid >> 3);
    const int bb   = sbid >> 6;                          // batch
    const int tile = sbid & 63;
    const int h0   = (tile >> 1) << 2;                   // output row base
    const int w0   = (tile & 1) << 6;                    // output col base

    // DMA chunk assignment: 17 x 1024B chunks; wave0: j 0..4, wave k: 4k+1..4k+4
    const int j0 = (wv == 0) ? 0 : (wv * 4 + 1);
    const int nj = (wv == 0) ? 5 : 4;
    unsigned go[5];                                      // per-lane global offsets
    #pragma unroll
    for (int jj = 0; jj < 5; ++jj) {
        const int off = (j0 + jj) * 1024 + lane * 16;    // LDS offset of this lane's 16B
        const int r   = off / ROWB;                      // staged row 0..7
        go[jj] = (unsigned)(r * GROW + (off - r * ROWB));
    }
    const char* xTb = (const char*)xT + (size_t)bb * GB + (size_t)h0 * GROW + (size_t)w0 * 32;

    auto DMA = [&](int s, int wbuf) {                    // stage s -> buf wbuf
        const char* sb = xTb + (size_t)s * GSPL;
        #pragma unroll
        for (int jj = 0; jj < 5; ++jj) {
            if (jj < nj) {
                __builtin_amdgcn_global_load_lds(
                    (const __attribute__((address_space(1))) u32*)(sb + go[jj]),
                    (__attribute__((address_space(3))) u32*)(lds + wbuf * BUFB + (j0 + jj) * 1024),
                    16, 0, 0);
            }
        }
    };

    f32x16 acc[2][4];                                    // [oc 32-half][output row]
    #pragma unroll
    for (int i = 0; i < 2; ++i)
        #pragma unroll
        for (int j = 0; j < 4; ++j)
            #pragma unroll
            for (int k = 0; k < 16; ++k) acc[i][j][k] = 0.f;

    bf16x8 A[2][5][2];                                   // A dbuf [parity][kh][m]
    const u16* cbA0 = cb + (wave_m * 64 + l31) * 128 + h2 * 8;

    auto ALOAD = [&](auto Pc, int kw, int s) {
        constexpr int P = decltype(Pc)::value;
        const u16* ab = cbA0 + kw * 16384 + s * 16;
        #pragma unroll
        for (int kh = 0; kh < 5; ++kh) {
            A[P][kh][0] = *reinterpret_cast<const bf16x8*>(ab + kh * 81920);
            A[P][kh][1] = *reinterpret_cast<const bf16x8*>(ab + kh * 81920 + 4096);
        }
    };

    auto COMPUTE = [&](auto Pc, auto KWc, auto RBc) {    // 8 ds_read -> 40 MFMA
        constexpr int P  = decltype(Pc)::value;
        constexpr int KW = decltype(KWc)::value;
        constexpr int RB = decltype(RBc)::value;
        const unsigned char* lb = &lds[RB * BUFB + (wave_q * 32 + l31 + KW) * 32 + h2 * 16];
        __builtin_amdgcn_s_setprio(1);
        #pragma unroll
        for (int rp = 0; rp < 8; ++rp) {
            const bf16x8 b = *reinterpret_cast<const bf16x8*>(lb + rp * ROWB);
            #pragma unroll
            for (int kh = 0; kh < 5; ++kh) {
                const int n = rp - kh;
                if (0 <= n && n < 4) {
                    acc[0][n] = __builtin_amdgcn_mfma_f32_32x32x16_bf16(A[P][kh][0], b, acc[0][n], 0, 0, 0);
                    acc[1][n] = __builtin_amdgcn_mfma_f32_32x32x16_bf16(A[P][kh][1], b, acc[1][n], 0, 0, 0);
                }
            }
        }
        __builtin_amdgcn_s_setprio(0);
    };

    // prologue: DMA stage 0 into buf 0; A(s=0,c0) into parity 0
    DMA(0, 0);
    ALOAD(IC<0>{}, 0, 0);
    asm volatile("s_waitcnt vmcnt(0)" ::: "memory");
    __builtin_amdgcn_s_barrier();
    __builtin_amdgcn_sched_barrier(0);

    // stage s: reads buf s&1; DMA(s+1) into buf (s+1)&1; A parity (s+k)&1
    auto STAGE = [&](auto SPc, int s) {
        constexpr int SP = decltype(SPc)::value;         // = s & 1
        constexpr int OP = SP ^ 1;
        const bool pfon = (s < 7);
        if (pfon) DMA(s + 1, OP);
        ALOAD(IC<OP>{}, 1, s);
        COMPUTE(IC<SP>{}, IC<0>{}, IC<SP>{});
        ALOAD(IC<SP>{}, 2, s);
        COMPUTE(IC<OP>{}, IC<1>{}, IC<SP>{});
        ALOAD(IC<OP>{}, 3, s);
        COMPUTE(IC<SP>{}, IC<2>{}, IC<SP>{});
        ALOAD(IC<SP>{}, 4, s);
        COMPUTE(IC<OP>{}, IC<3>{}, IC<SP>{});
        if (pfon) ALOAD(IC<OP>{}, 0, s + 1);             // par(s+1,0) = OP
        COMPUTE(IC<SP>{}, IC<4>{}, IC<SP>{});
        asm volatile("s_waitcnt vmcnt(0) lgkmcnt(0)" ::: "memory");
        __builtin_amdgcn_s_barrier();
        __builtin_amdgcn_sched_barrier(0);
    };

    #pragma unroll 1
    for (int sp = 0; sp < 4; ++sp) {
        STAGE(IC<0>{}, 2 * sp);
        STAGE(IC<1>{}, 2 * sp + 1);
    }

    // epilogue: D frag (32x32): col=lane&31 -> w, row=(reg&3)+8*(reg>>2)+4*h2 -> oc
    const int wpix = w0 + wave_q * 32 + l31;
    #pragma unroll
    for (int m = 0; m < 2; ++m)
        #pragma unroll
        for (int reg = 0; reg < 16; ++reg) {
            const int oc = wave_m * 64 + m * 32 + (reg & 3) + ((reg >> 2) << 3) + (h2 << 2);
            float* op = out + ((size_t)(bb * 128 + oc) * 128 + h0) * 128 + wpix;
            #pragma unroll
            for (int n = 0; n < 4; ++n)
                op[n * 128] = acc[m][n][reg];
        }
}

// ---------------- fallback (R7, proven 246 us) if ws too small for xT
constexpr int FROW = 68 * 48;
constexpr int FBUF = 8 * FROW;

__global__ void __launch_bounds__(256, 2)
conv_mfma_fb(const float* __restrict__ x,
             const u16*   __restrict__ cb,
             float*       __restrict__ out)
{
    __shared__ unsigned char lds[2 * FBUF];
    const int tid = threadIdx.x, lane = tid & 63, wv = tid >> 6;
    const int wave_m = wv & 1, wave_q = wv >> 1, l31 = lane & 31, h2 = lane >> 5;
    const int bid = blockIdx.x;
    const int sbid = (bid & 7) * 128 + (bid >> 3);
    const int bb = sbid >> 6, tile = sbid & 63;
    const int h0 = (tile >> 1) << 2, w0 = (tile & 1) << 6;
    const int wc = tid & 63, ic8 = (tid >> 6) & 1, rh = (tid >> 7) & 1;
    const int hsel = tid & 3;
    const int wcolH = (hsel < 2) ? (hsel - 2) : (62 + hsel);
    const int ic8H = (tid >> 2) & 1, rH = tid >> 3, hIdxH = wcolH + 2;

    f32x16 acc[2][4];
    #pragma unroll
    for (int i = 0; i < 2; ++i)
        #pragma unroll
        for (int j = 0; j < 4; ++j)
            #pragma unroll
            for (int k = 0; k < 16; ++k) acc[i][j][k] = 0.f;

    float pf[4][8]; float pfh[8];
    const float* xbase = x + (size_t)bb * (128 * 16384);
    const u16* cbA0 = cb + (wave_m * 64 + l31) * 128 + h2 * 8;

    auto ISSUE = [&](auto Uc, int s) {
        constexpr int U = decltype(Uc)::value;
        const int hp = h0 - 2 + 2 * U + rh;
        if ((unsigned)hp < 128u) {
            const float* px = xbase + (size_t)(s * 16 + ic8 * 8) * 16384 + hp * 128 + w0 + wc;
            #pragma unroll
            for (int j = 0; j < 8; ++j) pf[U][j] = px[(size_t)j * 16384];
        } else {
            #pragma unroll
            for (int j = 0; j < 8; ++j) pf[U][j] = 0.f;
        }
    };
    auto ISSUEH = [&](int s) {
        if (tid < 64) {
            const int hp = h0 - 2 + rH, gc = w0 + wcolH;
            if ((unsigned)hp < 128u && (unsigned)gc < 128u) {
                const float* px = xbase + (size_t)(s * 16 + ic8H * 8) * 16384 + hp * 128 + gc;
                #pragma unroll
                for (int j = 0; j < 8; ++j) pfh[j] = px[(size_t)j * 16384];
            } else {
                #pragma unroll
                for (int j = 0; j < 8; ++j) pfh[j] = 0.f;
            }
        }
    };
    auto WRITE = [&](auto Uc, int wbuf) {
        constexpr int U = decltype(Uc)::value;
        u32x4 v;
        v[0] = pack2bf(pf[U][0], pf[U][1]); v[1] = pack2bf(pf[U][2], pf[U][3]);
        v[2] = pack2bf(pf[U][4], pf[U][5]); v[3] = pack2bf(pf[U][6], pf[U][7]);
        *reinterpret_cast<u32x4*>(&lds[wbuf * FBUF + (2 * U + rh) * FROW + (wc + 2) * 48 + ic8 * 16]) = v;
    };
    auto WRITEH = [&](int wbuf) {
        if (tid < 64) {
            u32x4 v;
            v[0] = pack2bf(pfh[0], pfh[1]); v[1] = pack2bf(pfh[2], pfh[3]);
            v[2] = pack2bf(pfh[4], pfh[5]); v[3] = pack2bf(pfh[6], pfh[7]);
            *reinterpret_cast<u32x4*>(&lds[wbuf * FBUF + rH * FROW + hIdxH * 48 + ic8H * 16]) = v;
        }
    };
    auto CLUSTER = [&](auto KWc, int s) {
        constexpr int KW = decltype(KWc)::value;
        const u16* abase = cbA0 + KW * 16384 + s * 16;
        bf16x8 A[5][2];
        #pragma unroll
        for (int kh = 0; kh < 5; ++kh) {
            A[kh][0] = *reinterpret_cast<const bf16x8*>(abase + kh * 81920);
            A[kh][1] = *reinterpret_cast<const bf16x8*>(abase + kh * 81920 + 4096);
        }
        const unsigned char* lb = &lds[(s & 1) * FBUF + (wave_q * 32 + l31 + KW) * 48 + h2 * 16];
        __builtin_amdgcn_s_setprio(1);
        #pragma unroll
        for (int rp = 0; rp < 8; ++rp) {
            const bf16x8 b = *reinterpret_cast<const bf16x8*>(lb + rp * FROW);
            #pragma unroll
            for (int kh = 0; kh < 5; ++kh) {
                const int n = rp - kh;
                if (0 <= n && n < 4) {
                    acc[0][n] = __builtin_amdgcn_mfma_f32_32x32x16_bf16(A[kh][0], b, acc[0][n], 0, 0, 0);
                    acc[1][n] = __builtin_amdgcn_mfma_f32_32x32x16_bf16(A[kh][1], b, acc[1][n], 0, 0, 0);
                }
            }
        }
        __builtin_amdgcn_s_setprio(0);
    };

    ISSUE(IC<0>{}, 0); ISSUE(IC<1>{}, 0); ISSUE(IC<2>{}, 0); ISSUE(IC<3>{}, 0); ISSUEH(0);
    WRITE(IC<0>{}, 0); WRITE(IC<1>{}, 0); WRITE(IC<2>{}, 0); WRITE(IC<3>{}, 0); WRITEH(0);
    __syncthreads();

    #pragma unroll 1
    for (int s = 0; s < 8; ++s) {
        const int nb = (s + 1) & 1;
        if (s < 7) {
            ISSUE(IC<0>{}, s + 1); ISSUE(IC<1>{}, s + 1);
            ISSUE(IC<2>{}, s + 1); ISSUE(IC<3>{}, s + 1); ISSUEH(s + 1);
        }
        CLUSTER(IC<0>{}, s);
        if (s < 7) WRITE(IC<0>{}, nb);
        CLUSTER(IC<1>{}, s);
        if (s < 7) WRITE(IC<1>{}, nb);
        CLUSTER(IC<2>{}, s);
        if (s < 7) WRITE(IC<2>{}, nb);
        CLUSTER(IC<3>{}, s);
        if (s < 7) { WRITE(IC<3>{}, nb); WRITEH(nb); }
        CLUSTER(IC<4>{}, s);
        __syncthreads();
    }

    const int wpix = w0 + wave_q * 32 + l31;
    #pragma unroll
    for (int m = 0; m < 2; ++m)
        #pragma unroll
        for (int reg = 0; reg < 16; ++reg) {
            const int oc = wave_m * 64 + m * 32 + (reg & 3) + ((reg >> 2) << 3) + (h2 << 2);
            float* op = out + ((size_t)(bb * 128 + oc) * 128 + h0) * 128 + wpix;
            #pragma unroll
            for (int n = 0; n < 4; ++n)
                op[n * 128] = acc[m][n][reg];
        }
}

extern "C" void kernel_launch(void* const* d_in, const int* in_sizes, int n_in,
                              void* d_out, int out_size, void* d_ws, size_t ws_size,
                              hipStream_t stream)
{
    const float* x    = (const float*)d_in[0];
    const float* wxx  = (const float*)d_in[1];
    const float* wi   = (const float*)d_in[2];
    const float* XX   = (const float*)d_in[3];
    const float* iden = (const float*)d_in[4];
    const int*   ixx  = (const int*)d_in[5];
    const int*   iid  = (const int*)d_in[6];

    const size_t XT_BYTES = 71368704ull;                 // 16*8*132*4224
    const size_t NEED     = XT_BYTES + 819200ull;

    if (ws_size >= NEED) {
        u16* xTb  = (u16*)d_ws;
        u16* cbuf = (u16*)((char*)d_ws + XT_BYTES);
        build_c<<<1600, 256, 0, stream>>>(wxx, wi, XX, iden, ixx, iid, cbuf);
        transpose_pad<<<17424, 256, 0, stream>>>(x, xTb);
        conv_mfma<<<1024, 256, 0, stream>>>(xTb, cbuf, (float*)d_out);
    } else {
        u16* cbuf = (u16*)d_ws;
        build_c<<<1600, 256, 0, stream>>>(wxx, wi, XX, iden, ixx, iid, cbuf);
        conv_mfma_fb<<<1024, 256, 0, stream>>>(x, cbuf, (float*)d_out);
    }
}

// Round 10
// 255.678 us; speedup vs baseline: 1.2827x; 1.2827x over previous
//
#include <hip/hip_runtime.h>
#include <hip/hip_bf16.h>
#include <utility>

typedef __bf16        bf16x8 __attribute__((ext_vector_type(8)));
typedef float         f32x16 __attribute__((ext_vector_type(16)));
typedef unsigned int  u32x4  __attribute__((ext_vector_type(4)));
typedef unsigned int   u32;
typedef unsigned short u16;

template<int N> using IC = std::integral_constant<int, N>;

__device__ __forceinline__ u16 f32_to_bf16(float f) {
    u32 u = __builtin_bit_cast(u32, f);
    u = (u + 0x7FFFu + ((u >> 16) & 1u)) >> 16;
    return (u16)u;
}
__device__ __forceinline__ u32 pack2bf(float a, float b) {
    return (u32)f32_to_bf16(a) | ((u32)f32_to_bf16(b) << 16);
}

// ---------------- kernel 1: build conv weights, bf16, layout [tap][oc][ic]
__global__ void build_c(const float* __restrict__ wxx,
                        const float* __restrict__ wid,
                        const float* __restrict__ XX,
                        const float* __restrict__ ident,
                        const int*   __restrict__ indsxx,
                        const int*   __restrict__ indsid,
                        u16*         __restrict__ cb)
{
    int idx = blockIdx.x * 256 + threadIdx.x;          // 25*128*128 = 409600
    if (idx >= 25 * 128 * 128) return;
    int b = idx & 127;            // ic2
    int a = (idx >> 7) & 127;     // oc2
    int t = idx >> 14;            // kh*5+kw
    int w2 = (a >> 1) * 64 + (b >> 1);
    float v = wxx[w2 * 5 + indsxx[t]] * XX[(a * 128 + b) * 25 + t]
            + ident[a * 128 + b]      * wid[w2 * 6 + indsid[t]];
    cb[idx] = f32_to_bf16(v);
}

// ---------------- kernel 2: implicit-GEMM conv, 32x32x16 bf16 MFMA
// 256 thr = 4 waves (2 oc-halves x 2 w-halves). Block: 64 oc x 4 rows x 64 w.
// Wave: 32 oc x 4 rows x 32 w -> acc = 64 AGPR; A inline = 5 frags (20 VGPR).
// Register diet targets <=170 total -> 3 blocks/CU (12 waves/CU) for latency hiding.
// LDS: dbuf [8 rows][68 wp][48 B] = 52224 B; 3 x 52224 = 156.7 KB <= 160 KB.
// 8 stages of 16 ic; stencil B-reuse: 8 ds_read -> 20 MFMAs per cluster.
constexpr int LDSROW = 68 * 48;        // 3264 B
constexpr int LDSBUF = 8 * LDSROW;     // 26112 B

__global__ void __launch_bounds__(256, 3)
conv_mfma(const float* __restrict__ x,
          const u16*   __restrict__ cb,
          float*       __restrict__ out)
{
    __shared__ unsigned char lds[2 * LDSBUF];

    const int tid    = threadIdx.x;
    const int lane   = tid & 63;
    const int wv     = tid >> 6;
    const int wave_m = wv & 1;                           // oc half of 64
    const int wave_q = wv >> 1;                          // w half of 64
    const int l31    = lane & 31;
    const int h2     = lane >> 5;                        // k-half within K=16

    // bijective XCD swizzle: 2048 blocks, 256 consecutive tiles per XCD.
    // within-XCD order: oc-group innermost, then w-tile, then h-tile, then batch
    const int bid = blockIdx.x;
    const int swz = (bid & 7) * 256 + (bid >> 3);
    const int g   = swz & 1;                             // oc group (64 oc)
    const int wt  = (swz >> 1) & 1;                      // w tile
    const int ht  = (swz >> 2) & 31;                     // h tile
    const int bb  = swz >> 7;                            // batch
    const int h0  = ht << 2;
    const int w0  = wt << 6;
    const int ocb = g << 6;

    // staging map: thread -> (w col 0..63, 8-ic half, row parity)
    const int wc  = tid & 63;
    const int ic8 = (tid >> 6) & 1;
    const int rh  = (tid >> 7) & 1;

    // halo map (threads 0..63): 4 cols x 2 ic8 x 8 rows
    const int hsel  = tid & 3;
    const int wcolH = (hsel < 2) ? (hsel - 2) : (62 + hsel);   // -2,-1,64,65
    const int ic8H  = (tid >> 2) & 1;
    const int rH    = tid >> 3;                          // 0..7 (tid<64)
    const int hIdxH = wcolH + 2;                         // 0,1,66,67

    f32x16 acc[4];                                       // 4 output rows = 64 AGPR
    #pragma unroll
    for (int j = 0; j < 4; ++j)
        #pragma unroll
        for (int k = 0; k < 16; ++k) acc[j][k] = 0.f;

    float pf[4][8];                                      // 4 in-flight units
    float pfh[8];                                        // halo unit

    const float* xbase = x + (size_t)bb * (128 * 16384);
    const u16*   cbA0  = cb + (ocb + wave_m * 32 + l31) * 128 + h2 * 8;

    auto ISSUE = [&](auto Uc, int s) {                   // unit U of stage s
        constexpr int U = decltype(Uc)::value;
        const int hp = h0 - 2 + 2 * U + rh;
        if ((unsigned)hp < 128u) {
            const float* px = xbase + (size_t)(s * 16 + ic8 * 8) * 16384 + hp * 128 + w0 + wc;
            #pragma unroll
            for (int j = 0; j < 8; ++j) pf[U][j] = px[(size_t)j * 16384];
        } else {
            #pragma unroll
            for (int j = 0; j < 8; ++j) pf[U][j] = 0.f;
        }
    };

    auto ISSUEH = [&](int s) {                           // halo unit (tid<64)
        if (tid < 64) {
            const int hp = h0 - 2 + rH;
            const int gc = w0 + wcolH;
            if ((unsigned)hp < 128u && (unsigned)gc < 128u) {
                const float* px = xbase + (size_t)(s * 16 + ic8H * 8) * 16384 + hp * 128 + gc;
                #pragma unroll
                for (int j = 0; j < 8; ++j) pfh[j] = px[(size_t)j * 16384];
            } else {
                #pragma unroll
                for (int j = 0; j < 8; ++j) pfh[j] = 0.f;
            }
        }
    };

    auto WRITE = [&](auto Uc, int wbuf) {
        constexpr int U = decltype(Uc)::value;
        u32x4 v;
        v[0] = pack2bf(pf[U][0], pf[U][1]);
        v[1] = pack2bf(pf[U][2], pf[U][3]);
        v[2] = pack2bf(pf[U][4], pf[U][5]);
        v[3] = pack2bf(pf[U][6], pf[U][7]);
        *reinterpret_cast<u32x4*>(&lds[wbuf * LDSBUF + (2 * U + rh) * LDSROW
                                       + (wc + 2) * 48 + ic8 * 16]) = v;
    };

    auto WRITEH = [&](int wbuf) {
        if (tid < 64) {
            u32x4 v;
            v[0] = pack2bf(pfh[0], pfh[1]);
            v[1] = pack2bf(pfh[2], pfh[3]);
            v[2] = pack2bf(pfh[4], pfh[5]);
            v[3] = pack2bf(pfh[6], pfh[7]);
            *reinterpret_cast<u32x4*>(&lds[wbuf * LDSBUF + rH * LDSROW
                                           + hIdxH * 48 + ic8H * 16]) = v;
        }
    };

    // pure compute cluster: 5 A-frags (L2) + 8 B-reads -> 20 MFMAs
    auto CLUSTER = [&](auto KWc, int s) {
        constexpr int KW = decltype(KWc)::value;
        const u16* abase = cbA0 + KW * 16384 + s * 16;
        bf16x8 A[5];
        #pragma unroll
        for (int kh = 0; kh < 5; ++kh)
            A[kh] = *reinterpret_cast<const bf16x8*>(abase + kh * 81920);
        const unsigned char* lb = &lds[(s & 1) * LDSBUF
                                       + (wave_q * 32 + l31 + KW) * 48 + h2 * 16];
        __builtin_amdgcn_s_setprio(1);
        #pragma unroll
        for (int rp = 0; rp < 8; ++rp) {
            const bf16x8 b = *reinterpret_cast<const bf16x8*>(lb + rp * LDSROW);
            #pragma unroll
            for (int kh = 0; kh < 5; ++kh) {
                const int n = rp - kh;
                if (0 <= n && n < 4)
                    acc[n] = __builtin_amdgcn_mfma_f32_32x32x16_bf16(A[kh], b, acc[n], 0, 0, 0);
            }
        }
        __builtin_amdgcn_s_setprio(0);
    };

    // prologue: stage 0 into buf 0
    ISSUE(IC<0>{}, 0); ISSUE(IC<1>{}, 0); ISSUE(IC<2>{}, 0); ISSUE(IC<3>{}, 0); ISSUEH(0);
    WRITE(IC<0>{}, 0); WRITE(IC<1>{}, 0); WRITE(IC<2>{}, 0); WRITE(IC<3>{}, 0); WRITEH(0);
    __syncthreads();

    #pragma unroll 1
    for (int s = 0; s < 8; ++s) {
        const int nb = (s + 1) & 1;
        if (s < 7) {                                     // next stage's loads in flight
            ISSUE(IC<0>{}, s + 1); ISSUE(IC<1>{}, s + 1);
            ISSUE(IC<2>{}, s + 1); ISSUE(IC<3>{}, s + 1); ISSUEH(s + 1);
        }
        CLUSTER(IC<0>{}, s);
        if (s < 7) WRITE(IC<0>{}, nb);
        CLUSTER(IC<1>{}, s);
        if (s < 7) WRITE(IC<1>{}, nb);
        CLUSTER(IC<2>{}, s);
        if (s < 7) WRITE(IC<2>{}, nb);
        CLUSTER(IC<3>{}, s);
        if (s < 7) { WRITE(IC<3>{}, nb); WRITEH(nb); }
        CLUSTER(IC<4>{}, s);
        __syncthreads();
    }

    // epilogue: D frag (32x32): col=lane&31 -> w, row=(reg&3)+8*(reg>>2)+4*h2 -> oc
    const int wpix = w0 + wave_q * 32 + l31;
    #pragma unroll
    for (int reg = 0; reg < 16; ++reg) {
        const int oc = ocb + wave_m * 32 + (reg & 3) + ((reg >> 2) << 3) + (h2 << 2);
        float* op = out + ((size_t)(bb * 128 + oc) * 128 + h0) * 128 + wpix;
        #pragma unroll
        for (int n = 0; n < 4; ++n)
            op[n * 128] = acc[n][reg];
    }
}

extern "C" void kernel_launch(void* const* d_in, const int* in_sizes, int n_in,
                              void* d_out, int out_size, void* d_ws, size_t ws_size,
                              hipStream_t stream)
{
    const float* x    = (const float*)d_in[0];
    const float* wxx  = (const float*)d_in[1];
    const float* wi   = (const float*)d_in[2];
    const float* XX   = (const float*)d_in[3];
    const float* iden = (const float*)d_in[4];
    const int*   ixx  = (const int*)d_in[5];
    const int*   iid  = (const int*)d_in[6];

    u16* cbuf = (u16*)d_ws;                              // 819200 B scratch

    build_c<<<1600, 256, 0, stream>>>(wxx, wi, XX, iden, ixx, iid, cbuf);
    conv_mfma<<<2048, 256, 0, stream>>>(x, cbuf, (float*)d_out);
}